// Round 1
// baseline (424.050 us; speedup 1.0000x reference)
//
#include <hip/hip_runtime.h>

namespace {
constexpr int kB = 512;
constexpr int kT = 200;
constexpr int kI = 784;
constexpr int kH = 128;
constexpr int kO = 10;
constexpr int kM = kB * kT;  // 102400 rows
constexpr float kBeta = 0.9f;
constexpr float kThr = 1.0f;
}  // namespace

// ---------------------------------------------------------------------------
// C[M][128] = A[M][K] . B[128][K]^T + bias.   K%16==0, M%128==0.
// 128x128 block tile, BK=16, 256 threads, 8x8 per-thread register tile.
// LDS stored transposed [BK][BM+4] so inner-loop reads are float4,
// +4 pad gives <=2-way bank aliasing (free).
// ---------------------------------------------------------------------------
template <int K>
__global__ __launch_bounds__(256, 2) void gemm_nt128(
    const float* __restrict__ A, const float* __restrict__ B,
    const float* __restrict__ bias, float* __restrict__ C) {
  constexpr int BM = 128, BK = 16;
  __shared__ float As[BK][BM + 4];
  __shared__ float Bs[BK][BM + 4];
  const int tid = threadIdx.x;
  const int tx = tid & 15;   // n-dim
  const int ty = tid >> 4;   // m-dim
  const int row0 = blockIdx.x * BM;

  float acc[8][8];
#pragma unroll
  for (int i = 0; i < 8; ++i)
#pragma unroll
    for (int j = 0; j < 8; ++j) acc[i][j] = 0.0f;

  for (int k0 = 0; k0 < K; k0 += BK) {
    __syncthreads();
#pragma unroll
    for (int l = 0; l < 2; ++l) {
      const int fi = tid + l * 256;       // 0..511
      const int row = fi >> 2;            // 0..127
      const int c4 = (fi & 3) * 4;        // 0,4,8,12
      const float4 va = *reinterpret_cast<const float4*>(
          &A[(size_t)(row0 + row) * K + k0 + c4]);
      As[c4 + 0][row] = va.x;
      As[c4 + 1][row] = va.y;
      As[c4 + 2][row] = va.z;
      As[c4 + 3][row] = va.w;
      const float4 vb = *reinterpret_cast<const float4*>(
          &B[(size_t)row * K + k0 + c4]);
      Bs[c4 + 0][row] = vb.x;
      Bs[c4 + 1][row] = vb.y;
      Bs[c4 + 2][row] = vb.z;
      Bs[c4 + 3][row] = vb.w;
    }
    __syncthreads();
#pragma unroll
    for (int kk = 0; kk < BK; ++kk) {
      float a[8], b[8];
      *reinterpret_cast<float4*>(&a[0]) =
          *reinterpret_cast<const float4*>(&As[kk][ty * 4]);
      *reinterpret_cast<float4*>(&a[4]) =
          *reinterpret_cast<const float4*>(&As[kk][64 + ty * 4]);
      *reinterpret_cast<float4*>(&b[0]) =
          *reinterpret_cast<const float4*>(&Bs[kk][tx * 4]);
      *reinterpret_cast<float4*>(&b[4]) =
          *reinterpret_cast<const float4*>(&Bs[kk][64 + tx * 4]);
#pragma unroll
      for (int i = 0; i < 8; ++i)
#pragma unroll
        for (int j = 0; j < 8; ++j) acc[i][j] = fmaf(a[i], b[j], acc[i][j]);
    }
  }

#pragma unroll
  for (int i = 0; i < 8; ++i) {
    const int m = (i < 4) ? (ty * 4 + i) : (64 + ty * 4 + (i - 4));
    const size_t r = (size_t)(row0 + m);
#pragma unroll
    for (int jh = 0; jh < 2; ++jh) {
      const int n = jh * 64 + tx * 4;
      float4 v;
      v.x = acc[i][jh * 4 + 0] + bias[n + 0];
      v.y = acc[i][jh * 4 + 1] + bias[n + 1];
      v.z = acc[i][jh * 4 + 2] + bias[n + 2];
      v.w = acc[i][jh * 4 + 3] + bias[n + 3];
      *reinterpret_cast<float4*>(&C[r * 128 + n]) = v;
    }
  }
}

// ---------------------------------------------------------------------------
// In-place LIF scan over time for a [B,T,128] current buffer.
// thread = (b,h). m_new = (beta*m + cur) - s_prev ; s = (m_new > thr).
// Explicit _rn intrinsics forbid FMA contraction so the recurrence matches
// numpy's op-by-op rounding exactly.
// ---------------------------------------------------------------------------
__global__ __launch_bounds__(256) void lif_scan(float* __restrict__ buf) {
  const int g = blockIdx.x * 256 + threadIdx.x;  // 0..65535
  const int b = g >> 7;
  const int h = g & 127;
  const size_t base = (size_t)b * kT * 128 + h;
  float m = 0.0f, s = 0.0f;
#pragma unroll 4
  for (int t = 0; t < kT; ++t) {
    const float cur = buf[base + (size_t)t * 128];
    m = __fsub_rn(__fadd_rn(__fmul_rn(kBeta, m), cur), s);
    s = (m > kThr) ? 1.0f : 0.0f;
    buf[base + (size_t)t * 128] = s;
  }
}

// ---------------------------------------------------------------------------
// GEMM3: cur3[M][10] = s2[M][128] . W3[10][128]^T + b3. 64 rows / block,
// 320 threads, A-tile + W3 staged in LDS, 2 outputs per thread.
// ---------------------------------------------------------------------------
__global__ __launch_bounds__(320) void gemm3_n10(
    const float* __restrict__ A, const float* __restrict__ W3,
    const float* __restrict__ b3, float* __restrict__ C) {
  __shared__ float Ss[64][132];
  __shared__ float Ws[10][132];
  __shared__ float bs[10];
  const int tid = threadIdx.x;
  const size_t row0 = (size_t)blockIdx.x * 64;

  {  // stage W3: 10*128 floats = 320 float4, exactly one per thread
    const int r = tid >> 5;
    const int c4 = (tid & 31) * 4;
    const float4 v = *reinterpret_cast<const float4*>(&W3[r * 128 + c4]);
    Ws[r][c4 + 0] = v.x;
    Ws[r][c4 + 1] = v.y;
    Ws[r][c4 + 2] = v.z;
    Ws[r][c4 + 3] = v.w;
    if (tid < 10) bs[tid] = b3[tid];
  }
  for (int fi = tid; fi < 2048; fi += 320) {  // 64 rows * 32 float4
    const int r = fi >> 5;
    const int c4 = (fi & 31) * 4;
    const float4 v =
        *reinterpret_cast<const float4*>(&A[(row0 + r) * 128 + c4]);
    Ss[r][c4 + 0] = v.x;
    Ss[r][c4 + 1] = v.y;
    Ss[r][c4 + 2] = v.z;
    Ss[r][c4 + 3] = v.w;
  }
  __syncthreads();

#pragma unroll
  for (int l = 0; l < 2; ++l) {
    const int idx = tid + l * 320;  // 0..639
    const int r = idx / 10;
    const int o = idx - r * 10;
    float acc = bs[o];
#pragma unroll
    for (int k = 0; k < 128; k += 4) {
      const float4 a = *reinterpret_cast<const float4*>(&Ss[r][k]);
      const float4 w = *reinterpret_cast<const float4*>(&Ws[o][k]);
      acc = fmaf(a.x, w.x, acc);
      acc = fmaf(a.y, w.y, acc);
      acc = fmaf(a.z, w.z, acc);
      acc = fmaf(a.w, w.w, acc);
    }
    C[(row0 + r) * 10 + o] = acc;
  }
}

// ---------------------------------------------------------------------------
// Output LIF scan: thread = (b,o), reads cur3[(b*T+t)*10+o],
// writes spikes to out[t*B*10 + b*10 + o]  (layout [T,B,O]).
// ---------------------------------------------------------------------------
__global__ __launch_bounds__(256) void lif_scan_out(
    const float* __restrict__ cur3, float* __restrict__ out) {
  const int g = blockIdx.x * 256 + threadIdx.x;  // 0..5119
  if (g >= kB * kO) return;
  const int b = g / kO;
  const int o = g - b * kO;
  float m = 0.0f, s = 0.0f;
#pragma unroll 4
  for (int t = 0; t < kT; ++t) {
    const float c = cur3[((size_t)b * kT + t) * kO + o];
    m = __fsub_rn(__fadd_rn(__fmul_rn(kBeta, m), c), s);
    s = (m > kThr) ? 1.0f : 0.0f;
    out[(size_t)t * (kB * kO) + g] = s;
  }
}

extern "C" void kernel_launch(void* const* d_in, const int* in_sizes, int n_in,
                              void* d_out, int out_size, void* d_ws,
                              size_t ws_size, hipStream_t stream) {
  (void)in_sizes;
  (void)n_in;
  (void)out_size;
  (void)ws_size;
  const float* x = (const float*)d_in[0];    // [B,T,784]
  const float* W1 = (const float*)d_in[1];   // [128,784]
  const float* b1 = (const float*)d_in[2];   // [128]
  const float* W2 = (const float*)d_in[3];   // [128,128]
  const float* b2 = (const float*)d_in[4];   // [128]
  const float* W3 = (const float*)d_in[5];   // [10,128]
  const float* b3 = (const float*)d_in[6];   // [10]
  float* out = (float*)d_out;                // [T,B,10]

  float* buf0 = (float*)d_ws;                       // cur1 -> s1 ; later cur3
  float* buf1 = buf0 + (size_t)kM * kH;             // cur2 -> s2
  float* cur3 = buf0;                               // s1 dead after gemm2

  // Layer 1: x is [B,T,784] and row index r = b*T+t matches [B*T,784].
  gemm_nt128<kI><<<kM / 128, 256, 0, stream>>>(x, W1, b1, buf0);
  lif_scan<<<(kB * kH) / 256, 256, 0, stream>>>(buf0);
  // Layer 2
  gemm_nt128<kH><<<kM / 128, 256, 0, stream>>>(buf0, W2, b2, buf1);
  lif_scan<<<(kB * kH) / 256, 256, 0, stream>>>(buf1);
  // Layer 3
  gemm3_n10<<<kM / 64, 320, 0, stream>>>(buf1, W3, b3, cur3);
  lif_scan_out<<<(kB * kO + 255) / 256, 256, 0, stream>>>(cur3, out);
}